// Round 2
// baseline (747.774 us; speedup 1.0000x reference)
//
#include <hip/hip_runtime.h>

// Problem constants: B=4, C=64, N=512*512, K=400
constexpr int BB   = 4;
constexpr int CC   = 64;
constexpr int NPIX = 512 * 512;        // 262144
constexpr int KK   = 400;

constexpr int CH       = 32;           // channels per pass (2 halves)
constexpr int STRIDE   = CH + 1;       // 33: bank = (k*33+c)%32 = (k+c)%32
constexpr int CHUNKS   = 64;
constexpr int PPB      = NPIX / CHUNKS; // 4096 pixels per block
constexpr int ATHREADS = 512;
constexpr int NREP     = 8;            // replicated global accumulators

// ws layout (floats):
//   g_rep   [NREP][B][K][C]  = 819200 floats
//   g_cntr  [NREP][B][K]     =  12800 floats
//   g_means [B][K][C]        = 102400 floats      (total 3.74 MB)
constexpr size_t REP_F   = (size_t)BB * KK * CC;          // 102400
constexpr size_t CNT_F   = (size_t)BB * KK;               // 1600
constexpr size_t OFF_CNT = NREP * REP_F;                  // 819200
constexpr size_t OFF_MN  = OFF_CNT + NREP * CNT_F;        // 832000

// ---------------------------------------------------------------------------
// Stage 1: LDS histogram [K x 32ch], merged into 8 replicated global accums.
// grid = B * CHUNKS * 2 = 512 blocks
// ---------------------------------------------------------------------------
__global__ __launch_bounds__(ATHREADS) void accum_kernel(
    const float* __restrict__ feat,   // [B, C, N]
    const int*   __restrict__ idx,    // [B, N]
    float* __restrict__ g_rep,        // [NREP][B][K][C]
    float* __restrict__ g_cntr)       // [NREP][B][K]
{
    __shared__ float s_sums[KK * STRIDE];   // 52800 B
    __shared__ float s_cnt[KK];             //  1600 B

    const int t     = threadIdx.x;
    const int blk   = blockIdx.x;
    const int chalf = blk & 1;
    const int chunk = (blk >> 1) & (CHUNKS - 1);
    const int b     = blk >> 7;             // blk / (2*CHUNKS)
    const int p0    = chunk * PPB;

    for (int i = t; i < KK * STRIDE; i += ATHREADS) s_sums[i] = 0.0f;
    if (chalf == 0)
        for (int i = t; i < KK; i += ATHREADS) s_cnt[i] = 0.0f;
    __syncthreads();

    const int*   idx_b = idx + b * NPIX + p0;
    const float* fb    = feat + (size_t)b * CC * NPIX + (size_t)(chalf * CH) * NPIX + p0;

    for (int j = 0; j < PPB / 4 / ATHREADS; ++j) {   // 2 iterations
        const int g = j * ATHREADS + t;
        int4 kk = ((const int4*)idx_b)[g];
        if (chalf == 0) {
            atomicAdd(&s_cnt[kk.x], 1.0f);
            atomicAdd(&s_cnt[kk.y], 1.0f);
            atomicAdd(&s_cnt[kk.z], 1.0f);
            atomicAdd(&s_cnt[kk.w], 1.0f);
        }
        const int ax = kk.x * STRIDE, ay = kk.y * STRIDE;
        const int az = kk.z * STRIDE, aw = kk.w * STRIDE;
#pragma unroll 8
        for (int c = 0; c < CH; ++c) {
            float4 v = *(const float4*)(fb + (size_t)c * NPIX + 4 * g);
            atomicAdd(&s_sums[ax + c], v.x);
            atomicAdd(&s_sums[ay + c], v.y);
            atomicAdd(&s_sums[az + c], v.z);
            atomicAdd(&s_sums[aw + c], v.w);
        }
    }
    __syncthreads();

    // merge into replica (blk & 7) -> 8x less per-line contention
    float* gr = g_rep + (size_t)(blk & (NREP - 1)) * REP_F
                      + (size_t)b * KK * CC + chalf * CH;
    for (int e = t; e < KK * CH; e += ATHREADS) {
        int k = e >> 5, c = e & 31;
        atomicAdd(&gr[k * CC + c], s_sums[k * STRIDE + c]);
    }
    if (chalf == 0) {
        float* gc = g_cntr + (size_t)((blk >> 1) & (NREP - 1)) * CNT_F + (size_t)b * KK;
        for (int k = t; k < KK; k += ATHREADS)
            atomicAdd(&gc[k], s_cnt[k]);
    }
}

// ---------------------------------------------------------------------------
// Stage 2: fold replicas + counts -> means  (102400 threads, ~3 MB L2 reads)
// ---------------------------------------------------------------------------
__global__ __launch_bounds__(256) void reduce_means_kernel(
    const float* __restrict__ g_rep,
    const float* __restrict__ g_cntr,
    float* __restrict__ g_means)
{
    int e = blockIdx.x * 256 + threadIdx.x;
    if (e >= (int)REP_F) return;
    int b   = e / (KK * CC);
    int rem = e - b * KK * CC;
    int k   = rem >> 6;                 // C = 64
    float s = 0.0f, cnt = 0.0f;
#pragma unroll
    for (int r = 0; r < NREP; ++r) {
        s   += g_rep[(size_t)r * REP_F + e];
        cnt += g_cntr[(size_t)r * CNT_F + b * KK + k];
    }
    g_means[e] = s / fmaxf(cnt, 1.0f);
}

// ---------------------------------------------------------------------------
// Stage 3: gather via LDS-staged means table (per channel-half).
// grid = B * CHUNKS * 2 = 512 blocks
// ---------------------------------------------------------------------------
__global__ __launch_bounds__(ATHREADS) void gather_kernel(
    const float* __restrict__ means,  // [B, K, C]
    const int*   __restrict__ idx,    // [B, N]
    float* __restrict__ out)          // [B, C, N]
{
    __shared__ float s_m[KK * STRIDE];      // 52800 B

    const int t     = threadIdx.x;
    const int blk   = blockIdx.x;
    const int chalf = blk & 1;
    const int chunk = (blk >> 1) & (CHUNKS - 1);
    const int b     = blk >> 7;
    const int p0    = chunk * PPB;

    const float* mb = means + (size_t)b * KK * CC + chalf * CH;
    for (int i = t; i < KK * CH; i += ATHREADS) {
        int k = i >> 5, c = i & 31;
        s_m[k * STRIDE + c] = mb[k * CC + c];
    }
    __syncthreads();

    const int* idx_b = idx + b * NPIX + p0;
    float* ob = out + (size_t)b * CC * NPIX + (size_t)(chalf * CH) * NPIX + p0;

    for (int j = 0; j < PPB / 4 / ATHREADS; ++j) {   // 2 iterations
        const int g = j * ATHREADS + t;
        int4 kk = ((const int4*)idx_b)[g];
        const int ax = kk.x * STRIDE, ay = kk.y * STRIDE;
        const int az = kk.z * STRIDE, aw = kk.w * STRIDE;
#pragma unroll 8
        for (int c = 0; c < CH; ++c) {
            float4 o = { s_m[ax + c], s_m[ay + c], s_m[az + c], s_m[aw + c] };
            *(float4*)(ob + (size_t)c * NPIX + 4 * g) = o;
        }
    }
}

extern "C" void kernel_launch(void* const* d_in, const int* in_sizes, int n_in,
                              void* d_out, int out_size, void* d_ws, size_t ws_size,
                              hipStream_t stream) {
    const float* feat = (const float*)d_in[0];   // [B, C, N] fp32
    const int*   idx  = (const int*)d_in[1];     // [B, N] int32
    float* out     = (float*)d_out;
    float* g_rep   = (float*)d_ws;
    float* g_cntr  = g_rep + OFF_CNT;
    float* g_means = g_rep + OFF_MN;

    // zero the replicated accumulators + counts (means fully overwritten later)
    hipMemsetAsync(d_ws, 0, (NREP * REP_F + NREP * CNT_F) * sizeof(float), stream);

    accum_kernel<<<BB * CHUNKS * 2, ATHREADS, 0, stream>>>(feat, idx, g_rep, g_cntr);
    reduce_means_kernel<<<((int)REP_F + 255) / 256, 256, 0, stream>>>(g_rep, g_cntr, g_means);
    gather_kernel<<<BB * CHUNKS * 2, ATHREADS, 0, stream>>>(g_means, idx, out);
}